// Round 3
// baseline (318.702 us; speedup 1.0000x reference)
//
#include <hip/hip_runtime.h>

// Problem constants
#define NB   8
#define NC   256
#define HW   56
#define NPX  3136          // 56*56
#define RED  64
#define NG   16
#define GC   16
#define KS   7
#define KK   49
#define PADK 3
#define XPH  62            // padded rows: 3 + 56 + 3
#define XPW  64            // padded row stride: 3 + 56 + 5 (aligned)
#define XPSLICE (XPH * XPW)   // 3968 floats per channel slice

// ---------------------------------------------------------------------------
// K0: zero-padded copy of x into xpad[b][c][62][64].
// One block per (b,c) slice; 256 threads grid-stride the 3968 elements.
// Removes ALL bounds logic + most address math from K2's inner loop.
// ---------------------------------------------------------------------------
__global__ __launch_bounds__(256) void pad_kernel(
    const float* __restrict__ x, float* __restrict__ xpad) {
    int bc = blockIdx.x;                       // 0 .. NB*NC-1
    const float* xs = x + (size_t)bc * NPX;
    float* xd = xpad + (size_t)bc * XPSLICE;
#pragma unroll 4
    for (int e = threadIdx.x; e < XPSLICE; e += 256) {
        int row = e >> 6, col = e & 63;
        int h = row - PADK, w = col - PADK;
        float v = (h >= 0 && h < HW && w >= 0 && w < HW) ? xs[h * HW + w] : 0.0f;
        xd[e] = v;
    }
}

// ---------------------------------------------------------------------------
// K1: t = relu(bn1(conv1x1(x, w1)))   x:[B][256][3136] -> t:[B][64][3136]
// Block = 256 threads (4 waves); the 4 waves cover 4 consecutive rq-slices of
// the SAME 64-px tile -> x loads shared via L1. Batch-16 x loads for MLP.
// ---------------------------------------------------------------------------
__global__ __launch_bounds__(256) void conv1_kernel(
    const float* __restrict__ x, const float* __restrict__ w1,
    const float* __restrict__ g1, const float* __restrict__ be1,
    const float* __restrict__ mu1, const float* __restrict__ var1,
    float* __restrict__ t) {
    int lane = threadIdx.x & 63;
    int wv   = threadIdx.x >> 6;               // 0..3 (wave-uniform)
    int px = blockIdx.x * 64 + lane;
    int rq = blockIdx.y * 4 + wv;              // 0..7 -> outputs rq*8..rq*8+7
    int b  = blockIdx.z;

    const float* xb = x + (size_t)b * NC * NPX + px;
    float acc[8];
#pragma unroll
    for (int j = 0; j < 8; ++j) acc[j] = 0.0f;

#pragma unroll 1
    for (int c0 = 0; c0 < NC; c0 += 16) {
        float xv[16];
#pragma unroll
        for (int i = 0; i < 16; ++i) xv[i] = xb[(size_t)(c0 + i) * NPX];
#pragma unroll
        for (int j = 0; j < 8; ++j) {
            const float* wrow = w1 + (rq * 8 + j) * NC + c0;   // wave-uniform
#pragma unroll
            for (int i = 0; i < 16; ++i)
                acc[j] = fmaf(xv[i], wrow[i], acc[j]);
        }
    }

    float* tb = t + (size_t)b * RED * NPX + px;
#pragma unroll
    for (int j = 0; j < 8; ++j) {
        int o = rq * 8 + j;
        float inv = g1[o] * rsqrtf(var1[o] + 1e-5f);
        float v = acc[j] * inv + (be1[o] - mu1[o] * inv);
        tb[(size_t)o * NPX] = fmaxf(v, 0.0f);
    }
}

// ---------------------------------------------------------------------------
// K2: fused conv2(+bias) -> involution -> bn2 -> relu
// Grid (7 bands, 4 group-quads, 8 batches), block 448 = 7 waves.
// Lane = one pixel of an 8-row x 56-col band (no idle lanes).
//   - tv[64] = t[:, px] loaded ONCE into regs, reused for all 4 groups.
//   - per group, per tap-row i: compute wgt[0..6] (unrolled 64-FMA reductions,
//     4 chains; tv statically indexed), then apply the 7 taps to all 16
//     channel accumulators with immediate-offset loads from xpad (L1/L2 hits).
//   - no wgt[49]/xr[49] arrays -> no scratch, VGPR ~130.
// ---------------------------------------------------------------------------
__global__ __launch_bounds__(448) void involution_kernel(
    const float* __restrict__ xpad, const float* __restrict__ t,
    const float* __restrict__ w2, const float* __restrict__ b2,
    const float* __restrict__ g2, const float* __restrict__ be2,
    const float* __restrict__ mu2, const float* __restrict__ var2,
    float* __restrict__ out) {
    int tid  = threadIdx.x;                    // 0..447
    int band = blockIdx.x;                     // 0..6
    int gq   = blockIdx.y;                     // 0..3
    int b    = blockIdx.z;
    int px = band * 448 + tid;
    int h = px / HW, w = px % HW;

    // ---- load tv[64] once (coalesced, 64 loads in flight) ----
    const float* tb = t + (size_t)b * RED * NPX + px;
    float tv[64];
#pragma unroll
    for (int r = 0; r < 64; ++r) tv[r] = tb[(size_t)r * NPX];

    // pixel (h,w) center in padded coords = (h+3, w+3); tap (i,j) reads
    // padded (h+i, w+j)  ->  base at (h, w), offset i*XPW + j.
    const float* xpb = xpad + (size_t)b * NC * XPSLICE + h * XPW + w;
    float* ob = out + (size_t)b * NC * NPX + px;

#pragma unroll 1
    for (int gi = 0; gi < 4; ++gi) {
        int g = gq * 4 + gi;
        const float* wg = w2 + (size_t)g * KK * RED;      // [49][64] wave-uniform
        const float* bg = b2 + g * KK;
        const float* xg = xpb + (size_t)(g * GC) * XPSLICE;

        float oacc[GC];
#pragma unroll
        for (int cl = 0; cl < GC; ++cl) oacc[cl] = 0.0f;

#pragma unroll 1
        for (int i = 0; i < KS; ++i) {
            // --- phase A slice: wgt[j] for this tap row ---
            float wgt[KS];
#pragma unroll
            for (int j = 0; j < KS; ++j) {
                const float* wk = wg + (i * KS + j) * RED;    // wave-uniform
                float a0 = 0.f, a1 = 0.f, a2 = 0.f, a3 = 0.f;
#pragma unroll
                for (int r = 0; r < 64; r += 4) {
                    a0 = fmaf(tv[r],     wk[r],     a0);
                    a1 = fmaf(tv[r + 1], wk[r + 1], a1);
                    a2 = fmaf(tv[r + 2], wk[r + 2], a2);
                    a3 = fmaf(tv[r + 3], wk[r + 3], a3);
                }
                wgt[j] = ((a0 + a1) + (a2 + a3)) + bg[i * KS + j];
            }
            // --- phase B slice: apply row i's 7 taps to 16 channels ---
#pragma unroll
            for (int cl = 0; cl < GC; ++cl) {
                const float* xrow = xg + (size_t)cl * XPSLICE + i * XPW;
                float s0 = fmaf(wgt[0], xrow[0], oacc[cl]);
                float s1 = wgt[1] * xrow[1];
                s0 = fmaf(wgt[2], xrow[2], s0);
                s1 = fmaf(wgt[3], xrow[3], s1);
                s0 = fmaf(wgt[4], xrow[4], s0);
                s1 = fmaf(wgt[5], xrow[5], s1);
                s0 = fmaf(wgt[6], xrow[6], s0);
                oacc[cl] = s0 + s1;
            }
        }
        // --- bn2 + relu + store ---
#pragma unroll
        for (int cl = 0; cl < GC; ++cl) {
            int c = g * GC + cl;
            float inv = g2[c] * rsqrtf(var2[c] + 1e-5f);
            float v = oacc[cl] * inv + (be2[c] - mu2[c] * inv);
            ob[(size_t)c * NPX] = fmaxf(v, 0.0f);
        }
    }
}

// ---------------------------------------------------------------------------
extern "C" void kernel_launch(void* const* d_in, const int* in_sizes, int n_in,
                              void* d_out, int out_size, void* d_ws, size_t ws_size,
                              hipStream_t stream) {
    const float* x    = (const float*)d_in[0];
    const float* w1   = (const float*)d_in[1];
    const float* g1   = (const float*)d_in[2];
    const float* be1  = (const float*)d_in[3];
    const float* mu1  = (const float*)d_in[4];
    const float* var1 = (const float*)d_in[5];
    const float* w2   = (const float*)d_in[6];
    const float* b2   = (const float*)d_in[7];
    const float* g2   = (const float*)d_in[8];
    const float* be2  = (const float*)d_in[9];
    const float* mu2  = (const float*)d_in[10];
    const float* var2 = (const float*)d_in[11];
    float* outp = (float*)d_out;

    // ws layout: xpad (8*256*62*64*4 = 32.5 MB) then t (8*64*3136*4 = 6.4 MB)
    float* xpad = (float*)d_ws;
    float* t    = (float*)((char*)d_ws + (size_t)NB * NC * XPSLICE * sizeof(float));

    // K0: padded copy (2048 blocks x 4 waves, memory-bound)
    pad_kernel<<<NB * NC, 256, 0, stream>>>(x, xpad);
    // K1: conv1 + bn1 + relu
    conv1_kernel<<<dim3(NPX / 64, 2, NB), 256, 0, stream>>>(
        x, w1, g1, be1, mu1, var1, t);
    // K2: fused conv2 + involution + bn2 + relu
    involution_kernel<<<dim3(7, 4, NB), 448, 0, stream>>>(
        xpad, t, w2, b2, g2, be2, mu2, var2, outp);
}